// Round 1
// 97.641 us; speedup vs baseline: 1.0391x; 1.0391x over previous
//
#include <hip/hip_runtime.h>
#include <math.h>

#define NROWS 8192
#define DDIM  128
#define K20   28.853900817779268f        // 20 * log2(e)
#define K2    (K20 * K20)                // 832.5476
#define DTHR  8.3255f                    // 0.01 * K2 : diagonal mask (real pairs >= ~750)
#define JSPLIT 16                        // j-segments of 512 cols
#define NT    (NROWS / 16 / JSPLIT)      // 32 column-tiles (16 cols each) per segment

typedef _Float16 f16x8 __attribute__((ext_vector_type(8)));
typedef _Float16 f16x4 __attribute__((ext_vector_type(4)));
typedef _Float16 f16x2 __attribute__((ext_vector_type(2)));
typedef float    f32x4 __attribute__((ext_vector_type(4)));

#ifndef __has_builtin
#define __has_builtin(x) 0
#endif
#if __has_builtin(__builtin_amdgcn_fdot2)
#define HAVE_FDOT2 1
#else
#define HAVE_FDOT2 0
#endif

// Fragment-major layout for mfma_f32_16x16x32_f16 (16-row groups):
//   xf[g*2048 + kk*512 + l*8 + j] = x[i = g*16 + (l&15)][k = kk*32 + (l>>4)*8 + j]
// -> a wave's A/B fragment load for one k-chunk is one contiguous 1 KB dwordx4.
// ws layout (floats after xf): sums[0..N) = nL (sum exp(-40d)), [N..2N) = nS (sum exp(-20d))

// ---- fp32 -> f16 frag-major transform + zero sums/out ----
__global__ void convert_kernel(const float* __restrict__ x,
                               _Float16* __restrict__ xf,
                               float* __restrict__ sums,
                               float* __restrict__ out) {
    int idx = (blockIdx.x * 256 + threadIdx.x) * 4;    // flat (i,k) element index
    float4 v = *(const float4*)(x + idx);
    f16x4 h = { (_Float16)v.x, (_Float16)v.y, (_Float16)v.z, (_Float16)v.w };
    const int i = idx >> 7, k = idx & 127;             // k multiple of 4
    const int lane = (((k >> 3) & 3) << 4) | (i & 15);
    const int dst = (i >> 4) * 2048 + (k >> 5) * 512 + lane * 8 + (k & 7);
    *(f16x4*)(xf + dst) = h;
    if (threadIdx.x < 16) sums[blockIdx.x * 16 + threadIdx.x] = 0.0f;  // 1024*16 = 2*NROWS
    if (blockIdx.x == 0 && threadIdx.x == 0) out[0] = 0.0f;
}

// per-element negative-pair math: d2s = (20*log2e)^2 * d^2, tt = exp(-20d)
__device__ __forceinline__ void epi(const f32x4 acc, float* nLp, float* nSp) {
    #pragma unroll
    for (int r = 0; r < 4; ++r) {
        float d2s = fmaf(-2.0f * K2, acc[r], 2.0f * K2);
        float ds  = __builtin_amdgcn_sqrtf(d2s);             // NaN on diag, masked below
        float tt  = __builtin_amdgcn_exp2f(-ds);             // exp(-20 d)
        tt = (d2s < DTHR) ? 0.0f : tt;                       // exact diagonal exclusion
        nSp[r] += tt;
        nLp[r] = fmaf(tt, tt, nLp[r]);                       // exp(-40 d)
    }
}

// ---- main pair kernel. Wave owns a 32-row strip (two 16-row A fragments) x
//      512-col segment walked as 32 col-tiles of 16. Two 16x16x32 MFMAs per
//      tile (independent acc chains). B tiles register-double-buffered: loads
//      for tile g+1 issue before the MFMA/epilogue of tile g, hiding L2
//      latency in-wave. Small acc state (8 + 16 regs) keeps total VGPR ~105
//      -> 4 waves/SIMD resident (vs ~3 before). Block's 4 waves share the
//      segment (L1 reuse). Diagonal excluded by value; positives fixed in
//      finalize. ----
__global__ __launch_bounds__(256, 4) void pair_kernel(
        const _Float16* __restrict__ xf,
        float* __restrict__ sums) {
    const int w = threadIdx.x >> 6;
    const int lane = threadIdx.x & 63;
    const int ig = blockIdx.x * 4 + w;            // 32-row strip, 0..63
    const int i0 = ig * 32;
    const int jt0 = blockIdx.y * NT;              // first 16-col tile of segment

    // A fragments resident: 2 strips x 4 k-chunks, one 1 KB coalesced load each
    const _Float16* ab = xf + (size_t)(ig * 2) * 2048 + lane * 8;
    f16x8 a0[4], a1[4];
    #pragma unroll
    for (int kk = 0; kk < 4; ++kk) {
        a0[kk] = *(const f16x8*)(ab + kk * 512);
        a1[kk] = *(const f16x8*)(ab + 2048 + kk * 512);
    }

    float nL[8], nS[8];
    #pragma unroll
    for (int r = 0; r < 8; ++r) { nL[r] = 0.f; nS[r] = 0.f; }

    const _Float16* bbase = xf + (size_t)jt0 * 2048 + lane * 8;

    // prologue: tile 0 into b0
    f16x8 b0[4], b1[4];
    #pragma unroll
    for (int kk = 0; kk < 4; ++kk) b0[kk] = *(const f16x8*)(bbase + kk * 512);

    for (int g = 0; g < NT; g += 2) {
        {   // prefetch tile g+1 while tile g computes
            const _Float16* p = bbase + (size_t)(g + 1) * 2048;
            #pragma unroll
            for (int kk = 0; kk < 4; ++kk) b1[kk] = *(const f16x8*)(p + kk * 512);
        }
        {
            f32x4 acc0 = {0.f,0.f,0.f,0.f}, acc1 = {0.f,0.f,0.f,0.f};
            #pragma unroll
            for (int kk = 0; kk < 4; ++kk) {
                acc0 = __builtin_amdgcn_mfma_f32_16x16x32_f16(a0[kk], b0[kk], acc0, 0, 0, 0);
                acc1 = __builtin_amdgcn_mfma_f32_16x16x32_f16(a1[kk], b0[kk], acc1, 0, 0, 0);
            }
            epi(acc0, nL, nS);
            epi(acc1, nL + 4, nS + 4);
        }
        {   // prefetch tile g+2 (wraps to 0 on last iter; harmless valid load)
            const _Float16* p = bbase + (size_t)((g + 2) & (NT - 1)) * 2048;
            #pragma unroll
            for (int kk = 0; kk < 4; ++kk) b0[kk] = *(const f16x8*)(p + kk * 512);
        }
        {
            f32x4 acc0 = {0.f,0.f,0.f,0.f}, acc1 = {0.f,0.f,0.f,0.f};
            #pragma unroll
            for (int kk = 0; kk < 4; ++kk) {
                acc0 = __builtin_amdgcn_mfma_f32_16x16x32_f16(a0[kk], b1[kk], acc0, 0, 0, 0);
                acc1 = __builtin_amdgcn_mfma_f32_16x16x32_f16(a1[kk], b1[kk], acc1, 0, 0, 0);
            }
            epi(acc0, nL, nS);
            epi(acc1, nL + 4, nS + 4);
        }
    }

    // reduce across the 16 column-lanes per group; C/D map: col=lane&15,
    // row = s*16 + (lane>>4)*4 + r  (16x16x32 mapping, m89/m91)
    #pragma unroll
    for (int s = 0; s < 2; ++s) {
        #pragma unroll
        for (int r = 0; r < 4; ++r) {
            float aa = nL[s * 4 + r], bb = nS[s * 4 + r];
            #pragma unroll
            for (int m = 1; m < 16; m <<= 1) {
                aa += __shfl_xor(aa, m, 64);
                bb += __shfl_xor(bb, m, 64);
            }
            if ((lane & 15) == 0) {
                const int row = i0 + s * 16 + (lane >> 4) * 4 + r;
                atomicAdd(&sums[row], aa);
                atomicAdd(&sums[NROWS + row], bb);
            }
        }
    }
}

// ---- finalize + positive-pair correction (reads xf in frag-major order).
//      Block owns 256 rows; thread = one row. Dot products via v_dot2_f32_f16
//      (2 f16 MACs/instr) where available. ----
__global__ void finalize_kernel(const _Float16* __restrict__ xf,
                                const float* __restrict__ sums,
                                float* __restrict__ out) {
    const int i = blockIdx.x * 256 + threadIdx.x;
    const int g = i >> 4, ri = i & 15, ii = i & 7;
    const _Float16* base = xf + (size_t)g * 2048;

    // row i, elements: xf[g*2048 + kk*512 + ((h<<4)|ri)*8 + 0..7]
    f16x8 xi[16];
    #pragma unroll
    for (int kk = 0; kk < 4; ++kk) {
        #pragma unroll
        for (int h = 0; h < 4; ++h)
            xi[kk * 4 + h] = *(const f16x8*)(base + kk * 512 + ((h << 4) | ri) * 8);
    }

    float pL = 0.f, pS = 0.f, subL = 0.f, subS = 0.f;
    #pragma unroll
    for (int jj = 0; jj < 8; ++jj) {
        if (jj == ii) continue;
        const int rj = ri - ii + jj;               // same 16-row group (classes 8-aligned)
        float dot = 0.f;
        #pragma unroll
        for (int kk = 0; kk < 4; ++kk) {
            #pragma unroll
            for (int h = 0; h < 4; ++h) {
                f16x8 av = xi[kk * 4 + h];
                f16x8 bv = *(const f16x8*)(base + kk * 512 + ((h << 4) | rj) * 8);
#if HAVE_FDOT2
                #pragma unroll
                for (int u = 0; u < 4; ++u) {
                    f16x2 pa = { av[2 * u], av[2 * u + 1] };
                    f16x2 pb = { bv[2 * u], bv[2 * u + 1] };
                    dot = __builtin_amdgcn_fdot2(pa, pb, dot, false);
                }
#else
                #pragma unroll
                for (int u = 0; u < 8; ++u)
                    dot = fmaf((float)av[u], (float)bv[u], dot);
#endif
            }
        }
        float d2 = fmaf(-2.f, dot, 2.f);
        float d  = sqrtf(fmaxf(d2, 1e-12f));           // reference clamp
        float tt = __builtin_amdgcn_exp2f(-d * K20);   // exp(-20 d)
        pS += __builtin_amdgcn_exp2f(d * K20);         // exp(+20 d)
        pL = fmaf(tt, tt, pL);
        float tp = (d2 * K2 < DTHR) ? 0.f : tt;        // what pair_kernel added
        subS += tp;
        subL = fmaf(tp, tp, subL);
    }

    float nLv = sums[i] - subL;
    float nSv = sums[NROWS + i] - subS;
    float aLr  = 1.0f - pL / (pL + nLv);
    float posL = logf(pS) - 16.0f;    // log(sum exp(20(d-0.8)))
    float negL = logf(nSv) + 22.0f;   // log(sum exp(20(1.1-d)))
    float v = aLr * (posL + negL);

    #pragma unroll
    for (int m = 32; m; m >>= 1) v += __shfl_xor(v, m, 64);
    __shared__ float partial[4];
    int wv = threadIdx.x >> 6, lane = threadIdx.x & 63;
    if (lane == 0) partial[wv] = v;
    __syncthreads();
    if (threadIdx.x == 0) {
        float s = partial[0] + partial[1] + partial[2] + partial[3];
        atomicAdd(out, s * (1.0f / NROWS));
    }
}

extern "C" void kernel_launch(void* const* d_in, const int* in_sizes, int n_in,
                              void* d_out, int out_size, void* d_ws, size_t ws_size,
                              hipStream_t stream) {
    const float* x = (const float*)d_in[0];
    float* out = (float*)d_out;

    _Float16* xf = (_Float16*)d_ws;              // 2 MB, fragment-major
    float* sums  = (float*)(xf + NROWS * DDIM);  // 2*NROWS floats

    convert_kernel<<<NROWS * DDIM / (256 * 4), 256, 0, stream>>>(x, xf, sums, out);
    dim3 grid(NROWS / 128, JSPLIT);              // 64 x 16 = 1024 blocks = 4096 waves
    pair_kernel<<<grid, 256, 0, stream>>>(xf, sums);
    finalize_kernel<<<NROWS / 256, 256, 0, stream>>>(xf, sums, out);
}